// Round 3
// baseline (12442.909 us; speedup 1.0000x reference)
//
#include <hip/hip_runtime.h>

#define NB 128
#define NP 512
#define NH 512
#define NS 512
#define NE 256
#define ND 15
#define TH 1536            // 3*NH
#define TARROWS 1023       // NP + NS - 1
#define NWG 128            // scan grid
#define SEQ_ELEMS ((size_t)NB * NS * ND)   // 983040, tar starts here in d_out

typedef __attribute__((ext_vector_type(8))) short s16x8;
typedef __attribute__((ext_vector_type(4))) float f32x4;

// ---- module-scope scratch (graph-safe, fully rewritten every call) ----
__device__ float g_attn[NB * NH];
__device__ float g_W1[ND * TH];
__device__ float g_b1[TH];
__device__ float g_x0[NB * TH];
__device__ float g_ca[NB * ND];
__device__ float g_bb[NB * 2048];
__device__ __attribute__((aligned(16))) unsigned short g_Cm[2048 * NH];
__device__ __attribute__((aligned(16))) unsigned short g_st[(size_t)NB * 511 * NH]; // state mirror, bf16
__device__ unsigned g_bar;
__device__ unsigned g_isf32;   // 1 if inputs/outputs are float32, 0 if bf16

__device__ inline float b2f(unsigned short u) {
    return __uint_as_float(((unsigned)u) << 16);
}
__device__ inline unsigned short f2b(float f) {
    unsigned u = __float_as_uint(f);
    unsigned r = u + 0x7fffu + ((u >> 16) & 1u);
    return (unsigned short)(r >> 16);
}
__device__ inline float ldin(const void* p, size_t i, int isf32) {
    return isf32 ? ((const float*)p)[i] : b2f(((const unsigned short*)p)[i]);
}
__device__ inline void stout(void* p, size_t i, float v, int isf32) {
    if (isf32) ((float*)p)[i] = v;
    else ((unsigned short*)p)[i] = f2b(v);
}
__device__ inline float sigm(float x) {
    x = fminf(fmaxf(x, -30.f), 30.f);
    return 1.f / (1.f + __expf(-x));
}
__device__ inline float tanh_(float x) {
    x = fminf(fmaxf(x, -15.f), 15.f);
    float t = __expf(-2.f * x);
    return (1.f - t) / (1.f + t);
}

// ---------------- probe: decide input dtype; also reset barrier ----------------
__global__ __launch_bounds__(256) void k_probe(const void* hs)
{
    __shared__ float red[256];
    const unsigned short* p = (const unsigned short*)hs;
    float mx = 0.f;
    for (int i = threadIdx.x; i < 8192; i += 256) {
        float a = fabsf(b2f(p[2 * i]));   // even shorts: bf16 elements OR f32 low-mantissa junk
        if (!(a <= 1e6f)) a = 3e38f;      // NaN/Inf -> huge
        mx = fmaxf(mx, a);
    }
    red[threadIdx.x] = mx;
    __syncthreads();
    for (int s = 128; s > 0; s >>= 1) {
        if (threadIdx.x < s) red[threadIdx.x] = fmaxf(red[threadIdx.x], red[threadIdx.x + s]);
        __syncthreads();
    }
    if (threadIdx.x == 0) {
        g_isf32 = (red[0] > 1e6f) ? 1u : 0u;
        __hip_atomic_store(&g_bar, 0u, __ATOMIC_RELAXED, __HIP_MEMORY_SCOPE_AGENT);
    }
}

// ---------------- K1a: W1 = Wemb@gru_k (15x1536), b1 = bemb@gru_k + gb0 ----------------
__global__ __launch_bounds__(256) void k_w1(const void* __restrict__ Wemb,
                                            const void* __restrict__ gk,
                                            const void* __restrict__ bemb,
                                            const void* __restrict__ gb)
{
    const int isf32 = (int)g_isf32;
    const int tid = threadIdx.x;
    const int j = blockIdx.x * 256 + tid;   // 0..1535
    __shared__ float we[ND * NE];
    __shared__ float be[NE];
    for (int i = tid; i < ND * NE; i += 256) we[i] = ldin(Wemb, i, isf32);
    for (int i = tid; i < NE; i += 256) be[i] = ldin(bemb, i, isf32);
    __syncthreads();
    float acc[ND];
#pragma unroll
    for (int d = 0; d < ND; ++d) acc[d] = 0.f;
    float accb = 0.f;
    for (int e = 0; e < NE; ++e) {
        float g = ldin(gk, (size_t)e * TH + j, isf32);
        accb += be[e] * g;
#pragma unroll
        for (int d = 0; d < ND; ++d) acc[d] += we[d * NE + e] * g;
    }
#pragma unroll
    for (int d = 0; d < ND; ++d) g_W1[(size_t)d * TH + j] = acc[d];
    g_b1[j] = accb + ldin(gb, j, isf32);
}

// ---------------- K0: attention (softmax, attn) + hs->tar copy (rows 0..511) ----------------
__global__ __launch_bounds__(256) void k_attn(const void* __restrict__ hs,
                                              const void* __restrict__ masks,
                                              const void* __restrict__ Wq,
                                              const void* __restrict__ bq,
                                              void* __restrict__ out)
{
    const int isf32 = (int)g_isf32;
    const int b = blockIdx.x, tid = threadIdx.x;
    const int wave = tid >> 6, lane = tid & 63;
    __shared__ float wq[NH];
    __shared__ float sc[NP];
    __shared__ float wred[8];
    for (int i = tid; i < NH; i += 256) wq[i] = ldin(Wq, i, isf32);
    __syncthreads();
    const float bqv = ldin(bq, 0, isf32);
    for (int p = wave; p < NP; p += 4) {
        float s = 0.f;
        if (isf32) {
            const float* hr = (const float*)hs + (size_t)b * NP * NH + (size_t)p * NH + lane * 8;
            const float4 v0 = *(const float4*)(hr);
            const float4 v1 = *(const float4*)(hr + 4);
            const float* w = wq + lane * 8;
            s = v0.x * w[0] + v0.y * w[1] + v0.z * w[2] + v0.w * w[3]
              + v1.x * w[4] + v1.y * w[5] + v1.z * w[6] + v1.w * w[7];
        } else {
            const s16x8 v = *(const s16x8*)((const unsigned short*)hs + (size_t)b * NP * NH + (size_t)p * NH + lane * 8);
#pragma unroll
            for (int j = 0; j < 8; ++j) s += b2f((unsigned short)v[j]) * wq[lane * 8 + j];
        }
#pragma unroll
        for (int off = 32; off > 0; off >>= 1) s += __shfl_down(s, off);
        if (lane == 0) sc[p] = s + bqv + ldin(masks, (size_t)b * NP + p, isf32) * -1e9f;
    }
    __syncthreads();
    float m = -3e38f;
    for (int i = tid; i < NP; i += 256) m = fmaxf(m, sc[i]);
#pragma unroll
    for (int off = 32; off > 0; off >>= 1) m = fmaxf(m, __shfl_down(m, off));
    if (lane == 0) wred[wave] = m;
    __syncthreads();
    if (tid == 0) wred[0] = fmaxf(fmaxf(wred[0], wred[1]), fmaxf(wred[2], wred[3]));
    __syncthreads();
    m = wred[0];
    float s = 0.f;
    for (int i = tid; i < NP; i += 256) { float e = __expf(sc[i] - m); sc[i] = e; s += e; }
#pragma unroll
    for (int off = 32; off > 0; off >>= 1) s += __shfl_down(s, off);
    if (lane == 0) wred[4 + wave] = s;
    __syncthreads();
    if (tid == 0) wred[4] = wred[4] + wred[5] + wred[6] + wred[7];
    __syncthreads();
    const float inv = 1.f / wred[4];
    __syncthreads();
    for (int i = tid; i < NP; i += 256) sc[i] *= inv;
    __syncthreads();
    const int h0 = tid * 2;
    float a0 = 0.f, a1 = 0.f;
    if (isf32) {
        const float* hsb = (const float*)hs + (size_t)b * NP * NH;
        float* tarf = (float*)out + SEQ_ELEMS + (size_t)b * TARROWS * NH;
        for (int p = 0; p < NP; ++p) {
            float2 v = *(const float2*)(hsb + (size_t)p * NH + h0);
            float pr = sc[p];
            a0 += pr * v.x; a1 += pr * v.y;
            *(float2*)(tarf + (size_t)p * NH + h0) = v;
        }
    } else {
        const unsigned short* hsb = (const unsigned short*)hs + (size_t)b * NP * NH;
        unsigned short* tarb = (unsigned short*)out + SEQ_ELEMS + (size_t)b * TARROWS * NH;
        for (int p = 0; p < NP; ++p) {
            unsigned v = *(const unsigned*)(hsb + (size_t)p * NH + h0);
            float pr = sc[p];
            a0 += pr * b2f((unsigned short)(v & 0xffffu));
            a1 += pr * b2f((unsigned short)(v >> 16));
            *(unsigned*)(tarb + (size_t)p * NH + h0) = v;
        }
    }
    g_attn[b * NH + h0] = a0;
    g_attn[b * NH + h0 + 1] = a1;
}

// ---------------- K1c: CmatT[2048][512] bf16: blocks {Mz+Rz, Mr+Rr, Mh, Rh} ----------------
__global__ __launch_bounds__(256) void k_cmat(const void* __restrict__ Wlin,
                                              const void* __restrict__ grk)
{
    const int isf32 = (int)g_isf32;
    const int c = blockIdx.x;            // 0..2047
    const int tid = threadIdx.x;
    const int blk = c >> 9, u = c & 511;
    __shared__ float w1c[ND];
    const bool hasM = (blk < 3);
    const bool hasR = (blk != 2);
    const int j = (blk == 3) ? (1024 + u) : (blk * 512 + u);
    if (tid < ND && hasM) w1c[tid] = g_W1[(size_t)tid * TH + j];
    __syncthreads();
    for (int k = tid; k < NH; k += 256) {
        float v = 0.f;
        if (hasM) {
#pragma unroll
            for (int d = 0; d < ND; ++d) v += ldin(Wlin, (size_t)k * ND + d, isf32) * w1c[d];
        }
        if (hasR) v += ldin(grk, (size_t)k * TH + j, isf32);
        g_Cm[(size_t)c * NH + k] = f2b(v);
    }
}

// ---------------- K1d: c_attn, x0, per-batch bias bb[B][2048] ----------------
__global__ __launch_bounds__(256) void k_bb(const void* __restrict__ Wlin,
                                            const void* __restrict__ blin,
                                            const void* __restrict__ gb,
                                            const void* __restrict__ init_)
{
    const int isf32 = (int)g_isf32;
    const int b = blockIdx.x, tid = threadIdx.x;
    __shared__ float red[256 * ND];
    __shared__ float ca[ND];
    __shared__ float iv[ND];
    float part[ND];
#pragma unroll
    for (int d = 0; d < ND; ++d) part[d] = 0.f;
    for (int h = tid; h < NH; h += 256) {
        float av = g_attn[b * NH + h];
#pragma unroll
        for (int d = 0; d < ND; ++d) part[d] += av * ldin(Wlin, (size_t)(NH + h) * ND + d, isf32);
    }
#pragma unroll
    for (int d = 0; d < ND; ++d) red[tid * ND + d] = part[d];
    __syncthreads();
    for (int s = 128; s > 0; s >>= 1) {
        if (tid < s) {
#pragma unroll
            for (int d = 0; d < ND; ++d) red[tid * ND + d] += red[(tid + s) * ND + d];
        }
        __syncthreads();
    }
    if (tid < ND) {
        ca[tid] = red[tid] + ldin(blin, tid, isf32);
        iv[tid] = ldin(init_, b * ND + tid, isf32);
    }
    __syncthreads();
    for (int j = tid; j < TH; j += 256) {
        float a = g_b1[j];
#pragma unroll
        for (int d = 0; d < ND; ++d) a += iv[d] * g_W1[(size_t)d * TH + j];
        g_x0[(size_t)b * TH + j] = a;
    }
    for (int c = tid; c < 2048; c += 256) {
        int blk = c >> 9, u = c & 511;
        float v;
        if (blk == 3) {
            v = ldin(gb, TH + 1024 + u, isf32);
        } else {
            int j = blk * 512 + u;
            float a = g_b1[j];
#pragma unroll
            for (int d = 0; d < ND; ++d) a += ca[d] * g_W1[(size_t)d * TH + j];
            v = a;
            if (blk < 2) v += ldin(gb, TH + j, isf32);   // + gb1 for z,r blocks
        }
        g_bb[(size_t)b * 2048 + c] = v;
    }
    if (tid < ND) g_ca[b * ND + tid] = ca[tid];
}

// ---------------- K1b: GRU step 0, writes tar row 512 + mirror row 0 ----------------
__global__ __launch_bounds__(256) void k_step0(const void* __restrict__ hs,
                                               const void* __restrict__ grk,
                                               const void* __restrict__ gb,
                                               void* __restrict__ out)
{
    const int isf32 = (int)g_isf32;
    const int b = blockIdx.x, tid = threadIdx.x;
    __shared__ float s0[NH];
    __shared__ float h0[TH];
    for (int i = tid; i < NH; i += 256)
        s0[i] = ldin(hs, (size_t)b * NP * NH + (size_t)(NP - 1) * NH + i, isf32);
    __syncthreads();
    for (int j = tid; j < TH; j += 256) {
        float a = 0.f;
        for (int k = 0; k < NH; ++k) a += s0[k] * ldin(grk, (size_t)k * TH + j, isf32);
        h0[j] = a + ldin(gb, TH + j, isf32);
    }
    __syncthreads();
    for (int u = tid; u < NH; u += 256) {
        float xz = g_x0[(size_t)b * TH + u];
        float xr = g_x0[(size_t)b * TH + 512 + u];
        float xh = g_x0[(size_t)b * TH + 1024 + u];
        float z = sigm(xz + h0[u]);
        float r = sigm(xr + h0[512 + u]);
        float cand = tanh_(xh + r * h0[1024 + u]);
        float ns = z * s0[u] + (1.f - z) * cand;
        stout(out, SEQ_ELEMS + ((size_t)b * TARROWS + NP) * NH + u, ns, isf32);
        g_st[((size_t)b * 511 + 0) * NH + u] = f2b(ns);
    }
}

// ---------------- K2: persistent scan, steps t=1..510, grid barrier between steps ----------------
__global__ __launch_bounds__(256, 1) void k_scan(void* __restrict__ out)
{
    const int isf32 = (int)g_isf32;
    const int bi = blockIdx.x & 7;    // batch tile (16 rows)
    const int cj = blockIdx.x >> 3;   // hidden-unit slice (32 units)
    const int tid = threadIdx.x;
    const int wave = tid >> 6;        // gate block: 0=z 1=r 2=xh 3=hh
    const int lane = tid & 63;
    const int n15 = lane & 15, kq = lane >> 4;
    const int b0 = bi * 16;

    __shared__ unsigned short S[16 * 520];   // state tile, row stride 520 (16B aligned)
    __shared__ float zr[4 * 16 * 32];        // [blk][row][u]
    __shared__ float bbl[4 * 16 * 32];

    for (int i = tid; i < 2048; i += 256) {
        int blk = i >> 9, rem = i & 511, row = rem >> 5, u = rem & 31;
        bbl[i] = g_bb[(size_t)(b0 + row) * 2048 + blk * 512 + cj * 32 + u];
    }

    // weights resident in registers: 2 N-tiles x 16 k-steps
    s16x8 Bf[2][16];
#pragma unroll
    for (int n = 0; n < 2; ++n) {
        size_t col = (size_t)(wave * 512 + cj * 32 + n * 16 + n15);
#pragma unroll
        for (int ks = 0; ks < 16; ++ks)
            Bf[n][ks] = *(const s16x8*)(g_Cm + col * NH + ks * 32 + kq * 8);
    }
    __syncthreads();

    for (int t = 1; t <= 510; ++t) {
        {   // stage state_{t-1} tile from mirror -> LDS
            int r = tid >> 4, seg = tid & 15;
            const unsigned short* src = g_st + ((size_t)(b0 + r) * 511 + (t - 1)) * NH + seg * 32;
            unsigned short* dst = S + r * 520 + seg * 32;
            *(s16x8*)(dst)      = *(const s16x8*)(src);
            *(s16x8*)(dst + 8)  = *(const s16x8*)(src + 8);
            *(s16x8*)(dst + 16) = *(const s16x8*)(src + 16);
            *(s16x8*)(dst + 24) = *(const s16x8*)(src + 24);
        }
        __syncthreads();

        f32x4 acc0 = {0.f, 0.f, 0.f, 0.f};
        f32x4 acc1 = {0.f, 0.f, 0.f, 0.f};
#pragma unroll
        for (int ks = 0; ks < 16; ++ks) {
            s16x8 a = *(const s16x8*)(S + n15 * 520 + ks * 32 + kq * 8);
            acc0 = __builtin_amdgcn_mfma_f32_16x16x32_bf16(a, Bf[0][ks], acc0, 0, 0, 0);
            acc1 = __builtin_amdgcn_mfma_f32_16x16x32_bf16(a, Bf[1][ks], acc1, 0, 0, 0);
        }
#pragma unroll
        for (int reg = 0; reg < 4; ++reg) {
            int row = kq * 4 + reg;
            zr[wave * 512 + row * 32 + n15]      = acc0[reg];
            zr[wave * 512 + row * 32 + 16 + n15] = acc1[reg];
        }
        __syncthreads();

        for (int o = tid; o < 512; o += 256) {
            int row = o >> 5, u = o & 31;
            float z  = sigm(zr[row * 32 + u]        + bbl[row * 32 + u]);
            float r  = sigm(zr[512 + row * 32 + u]  + bbl[512 + row * 32 + u]);
            float xh =      zr[1024 + row * 32 + u] + bbl[1024 + row * 32 + u];
            float hh =      zr[1536 + row * 32 + u] + bbl[1536 + row * 32 + u];
            float cand = tanh_(xh + r * hh);
            float sprev = b2f(S[row * 520 + cj * 32 + u]);
            float ns = z * sprev + (1.f - z) * cand;
            g_st[((size_t)(b0 + row) * 511 + t) * NH + cj * 32 + u] = f2b(ns);
            stout(out, SEQ_ELEMS + ((size_t)(b0 + row) * TARROWS + NP + t) * NH + cj * 32 + u, ns, isf32);
        }

        // grid barrier (monotonic counter)
        __threadfence();
        __syncthreads();
        if (tid == 0) {
            __hip_atomic_fetch_add(&g_bar, 1u, __ATOMIC_RELEASE, __HIP_MEMORY_SCOPE_AGENT);
            unsigned target = (unsigned)(NWG * t);
            while (__hip_atomic_load(&g_bar, __ATOMIC_ACQUIRE, __HIP_MEMORY_SCOPE_AGENT) < target) {
                __builtin_amdgcn_s_sleep(2);
            }
        }
        __syncthreads();
        __threadfence();
    }
}

// ---------------- K3: seq[:,1:,:] = states @ Wlin_top + c_attn ----------------
__global__ __launch_bounds__(256) void k_seq(const void* __restrict__ Wlin,
                                             void* __restrict__ out)
{
    const int isf32 = (int)g_isf32;
    const int tid = threadIdx.x;
    __shared__ float wl[NH * ND];   // 30 KB
    for (int i = tid; i < NH * ND; i += 256) wl[i] = ldin(Wlin, i, isf32);
    __syncthreads();
    int idx = blockIdx.x * 256 + tid;   // over NB*511*ND
    if (idx < NB * 511 * ND) {
        int d = idx % ND;
        int t2 = idx / ND;
        int j = t2 % 511 + 1;
        int b = t2 / 511;
        const unsigned short* st = g_st + ((size_t)b * 511 + (j - 1)) * NH;
        float a = 0.f;
        for (int h = 0; h < NH; ++h) a += b2f(st[h]) * wl[h * ND + d];
        stout(out, ((size_t)b * NS + j) * ND + d, a + g_ca[b * ND + d], isf32);
    }
}

// ---------------- K3b: seq row 0 = init_point ----------------
__global__ __launch_bounds__(256) void k_seqinit(const void* __restrict__ init_,
                                                 void* __restrict__ out)
{
    const int isf32 = (int)g_isf32;
    int idx = blockIdx.x * 256 + threadIdx.x;
    if (idx < NB * ND) {
        int b = idx / ND, d = idx % ND;
        stout(out, (size_t)b * NS * ND + d, ldin(init_, idx, isf32), isf32);
    }
}

extern "C" void kernel_launch(void* const* d_in, const int* in_sizes, int n_in,
                              void* d_out, int out_size, void* d_ws, size_t ws_size,
                              hipStream_t stream)
{
    const void* hs    = d_in[0];
    const void* masks = d_in[1];
    const void* init_ = d_in[2];
    const void* Wq    = d_in[3];
    const void* bq    = d_in[4];
    const void* Wemb  = d_in[5];
    const void* bemb  = d_in[6];
    const void* gk    = d_in[7];
    const void* grk   = d_in[8];
    const void* gb    = d_in[9];
    const void* Wlin  = d_in[10];
    const void* blin  = d_in[11];

    k_probe<<<1, 256, 0, stream>>>(hs);
    k_w1<<<6, 256, 0, stream>>>(Wemb, gk, bemb, gb);
    k_attn<<<NB, 256, 0, stream>>>(hs, masks, Wq, bq, d_out);
    k_cmat<<<2048, 256, 0, stream>>>(Wlin, grk);
    k_bb<<<NB, 256, 0, stream>>>(Wlin, blin, gb, init_);
    k_step0<<<NB, 256, 0, stream>>>(hs, grk, gb, d_out);
    k_scan<<<NWG, 256, 0, stream>>>(d_out);
    k_seq<<<(NB * 511 * ND + 255) / 256, 256, 0, stream>>>(Wlin, d_out);
    k_seqinit<<<(NB * ND + 255) / 256, 256, 0, stream>>>(init_, d_out);
}

// Round 4
// 2068.728 us; speedup vs baseline: 6.0148x; 6.0148x over previous
//
#include <hip/hip_runtime.h>

#define NB 128
#define NP 512
#define NH 512
#define NS 512
#define NE 256
#define ND 15
#define TH 1536            // 3*NH
#define TARROWS 1023       // NP + NS - 1
#define NWG 128            // scan grid
#define SEQ_ELEMS ((size_t)NB * NS * ND)   // 983040, tar starts here in d_out

typedef __attribute__((ext_vector_type(8))) short s16x8;
typedef __attribute__((ext_vector_type(4))) float f32x4;
typedef __attribute__((ext_vector_type(4))) unsigned u32x4;

// ---- module-scope scratch (graph-safe, fully rewritten every call) ----
__device__ float g_attn[NB * NH];
__device__ float g_W1[ND * TH];
__device__ float g_b1[TH];
__device__ float g_x0[NB * TH];
__device__ float g_ca[NB * ND];
__device__ float g_bb[NB * 2048];
__device__ __attribute__((aligned(16))) unsigned short g_Cm[2048 * NH];
// state mirror, bf16 packed as dwords (2 cols per dword), [b][t][256]
__device__ __attribute__((aligned(16))) unsigned g_st32[(size_t)NB * 511 * 256];
__device__ unsigned g_bars[1024];   // 8 counters, 512 B apart (index bi*128)
__device__ unsigned g_isf32;        // 1 if inputs/outputs are float32, 0 if bf16

__device__ inline float b2f(unsigned short u) {
    return __uint_as_float(((unsigned)u) << 16);
}
__device__ inline unsigned short f2b(float f) {
    unsigned u = __float_as_uint(f);
    unsigned r = u + 0x7fffu + ((u >> 16) & 1u);
    return (unsigned short)(r >> 16);
}
__device__ inline float ldin(const void* p, size_t i, int isf32) {
    return isf32 ? ((const float*)p)[i] : b2f(((const unsigned short*)p)[i]);
}
__device__ inline void stout(void* p, size_t i, float v, int isf32) {
    if (isf32) ((float*)p)[i] = v;
    else ((unsigned short*)p)[i] = f2b(v);
}
__device__ inline float sigm(float x) {
    x = fminf(fmaxf(x, -30.f), 30.f);
    return 1.f / (1.f + __expf(-x));
}
__device__ inline float tanh_(float x) {
    x = fminf(fmaxf(x, -15.f), 15.f);
    float t = __expf(-2.f * x);
    return (1.f - t) / (1.f + t);
}

// ---------------- probe: decide input dtype; also reset barrier counters ----------------
__global__ __launch_bounds__(256) void k_probe(const void* hs)
{
    __shared__ float red[256];
    const unsigned short* p = (const unsigned short*)hs;
    float mx = 0.f;
    for (int i = threadIdx.x; i < 8192; i += 256) {
        float a = fabsf(b2f(p[2 * i]));   // even shorts: bf16 elements OR f32 low-mantissa junk
        if (!(a <= 1e6f)) a = 3e38f;      // NaN/Inf -> huge
        mx = fmaxf(mx, a);
    }
    red[threadIdx.x] = mx;
    __syncthreads();
    for (int s = 128; s > 0; s >>= 1) {
        if (threadIdx.x < s) red[threadIdx.x] = fmaxf(red[threadIdx.x], red[threadIdx.x + s]);
        __syncthreads();
    }
    if (threadIdx.x == 0) g_isf32 = (red[0] > 1e6f) ? 1u : 0u;
    if (threadIdx.x < 8)
        __hip_atomic_store(&g_bars[threadIdx.x * 128], 0u, __ATOMIC_RELAXED, __HIP_MEMORY_SCOPE_AGENT);
}

// ---------------- K1a: W1 = Wemb@gru_k (15x1536), b1 = bemb@gru_k + gb0 ----------------
__global__ __launch_bounds__(256) void k_w1(const void* __restrict__ Wemb,
                                            const void* __restrict__ gk,
                                            const void* __restrict__ bemb,
                                            const void* __restrict__ gb)
{
    const int isf32 = (int)g_isf32;
    const int tid = threadIdx.x;
    const int j = blockIdx.x * 256 + tid;   // 0..1535
    __shared__ float we[ND * NE];
    __shared__ float be[NE];
    for (int i = tid; i < ND * NE; i += 256) we[i] = ldin(Wemb, i, isf32);
    for (int i = tid; i < NE; i += 256) be[i] = ldin(bemb, i, isf32);
    __syncthreads();
    float acc[ND];
#pragma unroll
    for (int d = 0; d < ND; ++d) acc[d] = 0.f;
    float accb = 0.f;
    for (int e = 0; e < NE; ++e) {
        float g = ldin(gk, (size_t)e * TH + j, isf32);
        accb += be[e] * g;
#pragma unroll
        for (int d = 0; d < ND; ++d) acc[d] += we[d * NE + e] * g;
    }
#pragma unroll
    for (int d = 0; d < ND; ++d) g_W1[(size_t)d * TH + j] = acc[d];
    g_b1[j] = accb + ldin(gb, j, isf32);
}

// ---------------- K0: attention (softmax, attn) + hs->tar copy (rows 0..511) ----------------
__global__ __launch_bounds__(256) void k_attn(const void* __restrict__ hs,
                                              const void* __restrict__ masks,
                                              const void* __restrict__ Wq,
                                              const void* __restrict__ bq,
                                              void* __restrict__ out)
{
    const int isf32 = (int)g_isf32;
    const int b = blockIdx.x, tid = threadIdx.x;
    const int wave = tid >> 6, lane = tid & 63;
    __shared__ float wq[NH];
    __shared__ float sc[NP];
    __shared__ float wred[8];
    for (int i = tid; i < NH; i += 256) wq[i] = ldin(Wq, i, isf32);
    __syncthreads();
    const float bqv = ldin(bq, 0, isf32);
    for (int p = wave; p < NP; p += 4) {
        float s = 0.f;
        if (isf32) {
            const float* hr = (const float*)hs + (size_t)b * NP * NH + (size_t)p * NH + lane * 8;
            const float4 v0 = *(const float4*)(hr);
            const float4 v1 = *(const float4*)(hr + 4);
            const float* w = wq + lane * 8;
            s = v0.x * w[0] + v0.y * w[1] + v0.z * w[2] + v0.w * w[3]
              + v1.x * w[4] + v1.y * w[5] + v1.z * w[6] + v1.w * w[7];
        } else {
            const s16x8 v = *(const s16x8*)((const unsigned short*)hs + (size_t)b * NP * NH + (size_t)p * NH + lane * 8);
#pragma unroll
            for (int j = 0; j < 8; ++j) s += b2f((unsigned short)v[j]) * wq[lane * 8 + j];
        }
#pragma unroll
        for (int off = 32; off > 0; off >>= 1) s += __shfl_down(s, off);
        if (lane == 0) sc[p] = s + bqv + ldin(masks, (size_t)b * NP + p, isf32) * -1e9f;
    }
    __syncthreads();
    float m = -3e38f;
    for (int i = tid; i < NP; i += 256) m = fmaxf(m, sc[i]);
#pragma unroll
    for (int off = 32; off > 0; off >>= 1) m = fmaxf(m, __shfl_down(m, off));
    if (lane == 0) wred[wave] = m;
    __syncthreads();
    if (tid == 0) wred[0] = fmaxf(fmaxf(wred[0], wred[1]), fmaxf(wred[2], wred[3]));
    __syncthreads();
    m = wred[0];
    float s = 0.f;
    for (int i = tid; i < NP; i += 256) { float e = __expf(sc[i] - m); sc[i] = e; s += e; }
#pragma unroll
    for (int off = 32; off > 0; off >>= 1) s += __shfl_down(s, off);
    if (lane == 0) wred[4 + wave] = s;
    __syncthreads();
    if (tid == 0) wred[4] = wred[4] + wred[5] + wred[6] + wred[7];
    __syncthreads();
    const float inv = 1.f / wred[4];
    __syncthreads();
    for (int i = tid; i < NP; i += 256) sc[i] *= inv;
    __syncthreads();
    const int h0 = tid * 2;
    float a0 = 0.f, a1 = 0.f;
    if (isf32) {
        const float* hsb = (const float*)hs + (size_t)b * NP * NH;
        float* tarf = (float*)out + SEQ_ELEMS + (size_t)b * TARROWS * NH;
        for (int p = 0; p < NP; ++p) {
            float2 v = *(const float2*)(hsb + (size_t)p * NH + h0);
            float pr = sc[p];
            a0 += pr * v.x; a1 += pr * v.y;
            *(float2*)(tarf + (size_t)p * NH + h0) = v;
        }
    } else {
        const unsigned short* hsb = (const unsigned short*)hs + (size_t)b * NP * NH;
        unsigned short* tarb = (unsigned short*)out + SEQ_ELEMS + (size_t)b * TARROWS * NH;
        for (int p = 0; p < NP; ++p) {
            unsigned v = *(const unsigned*)(hsb + (size_t)p * NH + h0);
            float pr = sc[p];
            a0 += pr * b2f((unsigned short)(v & 0xffffu));
            a1 += pr * b2f((unsigned short)(v >> 16));
            *(unsigned*)(tarb + (size_t)p * NH + h0) = v;
        }
    }
    g_attn[b * NH + h0] = a0;
    g_attn[b * NH + h0 + 1] = a1;
}

// ---------------- K1c: CmatT[2048][512] bf16: blocks {Mz+Rz, Mr+Rr, Mh, Rh} ----------------
__global__ __launch_bounds__(256) void k_cmat(const void* __restrict__ Wlin,
                                              const void* __restrict__ grk)
{
    const int isf32 = (int)g_isf32;
    const int c = blockIdx.x;            // 0..2047
    const int tid = threadIdx.x;
    const int blk = c >> 9, u = c & 511;
    __shared__ float w1c[ND];
    const bool hasM = (blk < 3);
    const bool hasR = (blk != 2);
    const int j = (blk == 3) ? (1024 + u) : (blk * 512 + u);
    if (tid < ND && hasM) w1c[tid] = g_W1[(size_t)tid * TH + j];
    __syncthreads();
    for (int k = tid; k < NH; k += 256) {
        float v = 0.f;
        if (hasM) {
#pragma unroll
            for (int d = 0; d < ND; ++d) v += ldin(Wlin, (size_t)k * ND + d, isf32) * w1c[d];
        }
        if (hasR) v += ldin(grk, (size_t)k * TH + j, isf32);
        g_Cm[(size_t)c * NH + k] = f2b(v);
    }
}

// ---------------- K1d: c_attn, x0, per-batch bias bb[B][2048] ----------------
__global__ __launch_bounds__(256) void k_bb(const void* __restrict__ Wlin,
                                            const void* __restrict__ blin,
                                            const void* __restrict__ gb,
                                            const void* __restrict__ init_)
{
    const int isf32 = (int)g_isf32;
    const int b = blockIdx.x, tid = threadIdx.x;
    __shared__ float red[256 * ND];
    __shared__ float ca[ND];
    __shared__ float iv[ND];
    float part[ND];
#pragma unroll
    for (int d = 0; d < ND; ++d) part[d] = 0.f;
    for (int h = tid; h < NH; h += 256) {
        float av = g_attn[b * NH + h];
#pragma unroll
        for (int d = 0; d < ND; ++d) part[d] += av * ldin(Wlin, (size_t)(NH + h) * ND + d, isf32);
    }
#pragma unroll
    for (int d = 0; d < ND; ++d) red[tid * ND + d] = part[d];
    __syncthreads();
    for (int s = 128; s > 0; s >>= 1) {
        if (tid < s) {
#pragma unroll
            for (int d = 0; d < ND; ++d) red[tid * ND + d] += red[(tid + s) * ND + d];
        }
        __syncthreads();
    }
    if (tid < ND) {
        ca[tid] = red[tid] + ldin(blin, tid, isf32);
        iv[tid] = ldin(init_, b * ND + tid, isf32);
    }
    __syncthreads();
    for (int j = tid; j < TH; j += 256) {
        float a = g_b1[j];
#pragma unroll
        for (int d = 0; d < ND; ++d) a += iv[d] * g_W1[(size_t)d * TH + j];
        g_x0[(size_t)b * TH + j] = a;
    }
    for (int c = tid; c < 2048; c += 256) {
        int blk = c >> 9, u = c & 511;
        float v;
        if (blk == 3) {
            v = ldin(gb, TH + 1024 + u, isf32);
        } else {
            int j = blk * 512 + u;
            float a = g_b1[j];
#pragma unroll
            for (int d = 0; d < ND; ++d) a += ca[d] * g_W1[(size_t)d * TH + j];
            v = a;
            if (blk < 2) v += ldin(gb, TH + j, isf32);   // + gb1 for z,r blocks
        }
        g_bb[(size_t)b * 2048 + c] = v;
    }
    if (tid < ND) g_ca[b * ND + tid] = ca[tid];
}

// ---------------- K1b: GRU step 0, writes tar row 512 + mirror row 0 ----------------
__global__ __launch_bounds__(256) void k_step0(const void* __restrict__ hs,
                                               const void* __restrict__ grk,
                                               const void* __restrict__ gb,
                                               void* __restrict__ out)
{
    const int isf32 = (int)g_isf32;
    const int b = blockIdx.x, tid = threadIdx.x;
    __shared__ float s0[NH];
    __shared__ float h0[TH];
    for (int i = tid; i < NH; i += 256)
        s0[i] = ldin(hs, (size_t)b * NP * NH + (size_t)(NP - 1) * NH + i, isf32);
    __syncthreads();
    for (int j = tid; j < TH; j += 256) {
        float a = 0.f;
        for (int k = 0; k < NH; ++k) a += s0[k] * ldin(grk, (size_t)k * TH + j, isf32);
        h0[j] = a + ldin(gb, TH + j, isf32);
    }
    __syncthreads();
    // one thread -> two adjacent units (dword-packed mirror store)
    const int i = tid;              // 0..255
    float ns[2];
#pragma unroll
    for (int q = 0; q < 2; ++q) {
        int u = 2 * i + q;
        float xz = g_x0[(size_t)b * TH + u];
        float xr = g_x0[(size_t)b * TH + 512 + u];
        float xh = g_x0[(size_t)b * TH + 1024 + u];
        float z = sigm(xz + h0[u]);
        float r = sigm(xr + h0[512 + u]);
        float cand = tanh_(xh + r * h0[1024 + u]);
        ns[q] = z * s0[u] + (1.f - z) * cand;
        stout(out, SEQ_ELEMS + ((size_t)b * TARROWS + NP) * NH + u, ns[q], isf32);
    }
    unsigned pack = (unsigned)f2b(ns[0]) | ((unsigned)f2b(ns[1]) << 16);
    g_st32[((size_t)b * 511 + 0) * 256 + i] = pack;
}

// ---------------- K2: persistent scan, steps t=1..510 ----------------
// 8 independent groups (one per 16-row batch tile) x 16 WGs (32-col slices).
// State traffic is device-coherent (sc0/sc1); per-group relaxed counter barrier.
__global__ __launch_bounds__(256, 1) void k_scan(void* __restrict__ out)
{
    const int isf32 = (int)g_isf32;
    const int bi = blockIdx.x & 7;    // batch tile (16 rows) == barrier group
    const int cj = blockIdx.x >> 3;   // hidden-unit slice (32 units)
    const int tid = threadIdx.x;
    const int wave = tid >> 6;        // gate block: 0=z 1=r 2=xh 3=hh
    const int lane = tid & 63;
    const int n15 = lane & 15, kq = lane >> 4;
    const int b0 = bi * 16;
    unsigned* cnt = &g_bars[bi * 128];

    __shared__ __attribute__((aligned(16))) unsigned S32[16 * 260]; // state tile, row stride 260 dw (520 sh)
    __shared__ float zr[4 * 16 * 32];        // [blk][row][u]
    __shared__ float bbl[4 * 16 * 32];

    for (int i = tid; i < 2048; i += 256) {
        int blk = i >> 9, rem = i & 511, row = rem >> 5, u = rem & 31;
        bbl[i] = g_bb[(size_t)(b0 + row) * 2048 + blk * 512 + cj * 32 + u];
    }

    // weights resident in registers: 2 N-tiles x 16 k-steps
    s16x8 Bf[2][16];
#pragma unroll
    for (int n = 0; n < 2; ++n) {
        size_t col = (size_t)(wave * 512 + cj * 32 + n * 16 + n15);
#pragma unroll
        for (int ks = 0; ks < 16; ++ks)
            Bf[n][ks] = *(const s16x8*)(g_Cm + col * NH + ks * 32 + kq * 8);
    }

    const unsigned short* Ssh = (const unsigned short*)S32;
    const int prow = tid >> 4, pdc = tid & 15;   // pointwise: row, dword-col

    __syncthreads();

    for (int t = 1; t <= 510; ++t) {
        {   // stage state_{t-1} full 16x512 tile from mirror -> LDS (LLC-coherent loads)
            int r = tid >> 4, seg = tid & 15;
            const unsigned* gp = g_st32 + ((size_t)(b0 + r) * 511 + (t - 1)) * 256 + seg * 16;
            u32x4 v0, v1, v2, v3;
            asm volatile("global_load_dwordx4 %0, %1, off sc0 sc1"           : "=v"(v0) : "v"(gp));
            asm volatile("global_load_dwordx4 %0, %1, off offset:16 sc0 sc1" : "=v"(v1) : "v"(gp));
            asm volatile("global_load_dwordx4 %0, %1, off offset:32 sc0 sc1" : "=v"(v2) : "v"(gp));
            asm volatile("global_load_dwordx4 %0, %1, off offset:48 sc0 sc1" : "=v"(v3) : "v"(gp));
            asm volatile("s_waitcnt vmcnt(0)" ::: "memory");
            u32x4* Sv = (u32x4*)(S32 + r * 260 + seg * 16);
            Sv[0] = v0; Sv[1] = v1; Sv[2] = v2; Sv[3] = v3;
        }
        __syncthreads();

        f32x4 acc0 = {0.f, 0.f, 0.f, 0.f};
        f32x4 acc1 = {0.f, 0.f, 0.f, 0.f};
#pragma unroll
        for (int ks = 0; ks < 16; ++ks) {
            s16x8 a = *(const s16x8*)(Ssh + n15 * 520 + ks * 32 + kq * 8);
            acc0 = __builtin_amdgcn_mfma_f32_16x16x32_bf16(a, Bf[0][ks], acc0, 0, 0, 0);
            acc1 = __builtin_amdgcn_mfma_f32_16x16x32_bf16(a, Bf[1][ks], acc1, 0, 0, 0);
        }
#pragma unroll
        for (int reg = 0; reg < 4; ++reg) {
            int row = kq * 4 + reg;
            zr[wave * 512 + row * 32 + n15]      = acc0[reg];
            zr[wave * 512 + row * 32 + 16 + n15] = acc1[reg];
        }
        __syncthreads();

        // pointwise GRU: each thread handles 2 adjacent units of its row
        float ns[2];
#pragma unroll
        for (int q = 0; q < 2; ++q) {
            int u = pdc * 2 + q;
            float z  = sigm(zr[prow * 32 + u]        + bbl[prow * 32 + u]);
            float r  = sigm(zr[512 + prow * 32 + u]  + bbl[512 + prow * 32 + u]);
            float xh =      zr[1024 + prow * 32 + u] + bbl[1024 + prow * 32 + u];
            float hh =      zr[1536 + prow * 32 + u] + bbl[1536 + prow * 32 + u];
            float cand = tanh_(xh + r * hh);
            float sprev = b2f(Ssh[prow * 520 + cj * 32 + u]);
            ns[q] = z * sprev + (1.f - z) * cand;
        }
        unsigned pack = (unsigned)f2b(ns[0]) | ((unsigned)f2b(ns[1]) << 16);
        __hip_atomic_store(&g_st32[((size_t)(b0 + prow) * 511 + t) * 256 + cj * 16 + pdc],
                           pack, __ATOMIC_RELAXED, __HIP_MEMORY_SCOPE_AGENT);

        __syncthreads();   // drains vmcnt in every wave -> slice at LLC

        if (tid == 0) {
            __hip_atomic_fetch_add(cnt, 1u, __ATOMIC_RELAXED, __HIP_MEMORY_SCOPE_AGENT);
            __asm__ volatile("" ::: "memory");
        }

        // tar output write hidden under the poll (not read by other WGs)
        {
            size_t ti = SEQ_ELEMS + ((size_t)(b0 + prow) * TARROWS + NP + t) * NH + cj * 32 + pdc * 2;
            if (isf32) {
                float* p = (float*)out + ti;
                p[0] = ns[0]; p[1] = ns[1];
            } else {
                *(unsigned*)((unsigned short*)out + ti) = pack;
            }
        }

        if (tid == 0) {
            unsigned target = (unsigned)(16 * t);
            while (__hip_atomic_load(cnt, __ATOMIC_RELAXED, __HIP_MEMORY_SCOPE_AGENT) < target) {
                __builtin_amdgcn_s_sleep(1);
            }
        }
        __syncthreads();
    }
}

// ---------------- K3: seq[:,1:,:] = states @ Wlin_top + c_attn ----------------
__global__ __launch_bounds__(256) void k_seq(const void* __restrict__ Wlin,
                                             void* __restrict__ out)
{
    const int isf32 = (int)g_isf32;
    const int tid = threadIdx.x;
    __shared__ float wl[NH * ND];   // 30 KB
    for (int i = tid; i < NH * ND; i += 256) wl[i] = ldin(Wlin, i, isf32);
    __syncthreads();
    int idx = blockIdx.x * 256 + tid;   // over NB*511*ND
    if (idx < NB * 511 * ND) {
        int d = idx % ND;
        int t2 = idx / ND;
        int j = t2 % 511 + 1;
        int b = t2 / 511;
        const unsigned short* st = (const unsigned short*)g_st32 + ((size_t)b * 511 + (j - 1)) * NH;
        float a = 0.f;
        for (int h = 0; h < NH; ++h) a += b2f(st[h]) * wl[h * ND + d];
        stout(out, ((size_t)b * NS + j) * ND + d, a + g_ca[b * ND + d], isf32);
    }
}

// ---------------- K3b: seq row 0 = init_point ----------------
__global__ __launch_bounds__(256) void k_seqinit(const void* __restrict__ init_,
                                                 void* __restrict__ out)
{
    const int isf32 = (int)g_isf32;
    int idx = blockIdx.x * 256 + threadIdx.x;
    if (idx < NB * ND) {
        int b = idx / ND, d = idx % ND;
        stout(out, (size_t)b * NS * ND + d, ldin(init_, idx, isf32), isf32);
    }
}

extern "C" void kernel_launch(void* const* d_in, const int* in_sizes, int n_in,
                              void* d_out, int out_size, void* d_ws, size_t ws_size,
                              hipStream_t stream)
{
    const void* hs    = d_in[0];
    const void* masks = d_in[1];
    const void* init_ = d_in[2];
    const void* Wq    = d_in[3];
    const void* bq    = d_in[4];
    const void* Wemb  = d_in[5];
    const void* bemb  = d_in[6];
    const void* gk    = d_in[7];
    const void* grk   = d_in[8];
    const void* gb    = d_in[9];
    const void* Wlin  = d_in[10];
    const void* blin  = d_in[11];

    k_probe<<<1, 256, 0, stream>>>(hs);
    k_w1<<<6, 256, 0, stream>>>(Wemb, gk, bemb, gb);
    k_attn<<<NB, 256, 0, stream>>>(hs, masks, Wq, bq, d_out);
    k_cmat<<<2048, 256, 0, stream>>>(Wlin, grk);
    k_bb<<<NB, 256, 0, stream>>>(Wlin, blin, gb, init_);
    k_step0<<<NB, 256, 0, stream>>>(hs, grk, gb, d_out);
    k_scan<<<NWG, 256, 0, stream>>>(d_out);
    k_seq<<<(NB * 511 * ND + 255) / 256, 256, 0, stream>>>(Wlin, d_out);
    k_seqinit<<<(NB * ND + 255) / 256, 256, 0, stream>>>(init_, d_out);
}